// Round 8
// baseline (17217.311 us; speedup 1.0000x reference)
//
#include <hip/hip_runtime.h>
#include <hip/hip_bf16.h>
#include <math.h>

#define TDIM 1024
#define UDIM 512
#define NG   2048   // 4*U
#define NBLK 208

typedef __attribute__((ext_vector_type(8))) short short8;
typedef __attribute__((ext_vector_type(4))) float float4v;

// ---------------- workspace layout ----------------
#define OFF_U0T   ((size_t)0)                       // bf16 [2048][512]  gate-interleaved, transposed
#define SZ_U0T    ((size_t)NG*UDIM*2)
#define OFF_W1U1T (OFF_U0T + SZ_U0T)                // bf16 [2048][1024] (W1 rows 0-511, U1 rows 512-1023)
#define SZ_W1U1T  ((size_t)NG*1024*2)
#define OFF_W0P   (OFF_W1U1T + SZ_W1U1T)            // f32 [3][2048] permuted
#define SZ_W0P    ((size_t)3*NG*4)
#define OFF_B0P   (OFF_W0P + SZ_W0P)
#define OFF_B1P   (OFF_B0P + (size_t)NG*4)
#define OFF_STATE (OFF_B1P + (size_t)NG*4)
#define SZ_HB     ((size_t)512*UDIM*2)              // 512 KB per slot
#define SZ_HF     ((size_t)512*UDIM*4)              // 1 MB per slot
#define OFF_H0B   (OFF_STATE)                       // bf16 ring x4
#define OFF_H1B   (OFF_H0B + 4*SZ_HB)               // bf16 ring x4
#define OFF_H1F   (OFF_H1B + 4*SZ_HB)               // f32 ring x4 (FC input)
#define OFF_CNT   (OFF_H1F + 4*SZ_HF)               // progress counters
#define STATE_BYTES (8*SZ_HB + 4*SZ_HF + 4096)

#define HSLOT ((size_t)512*UDIM)                    // elements per bf16 slot
#define FSLOT ((size_t)512*UDIM)                    // floats per f32 slot

// counter layout (dwords from cnt):
//  P0G:  g*16 + nsl                  [0,64)    L0 per-producer, stores s+1 after step s
//  P1G:  64 + g*32 + half*16 + nsl   [64,192)  L1 per-producer, stores s after step s
//  PF :  192 + g*16                  [192,256) FC aggregated fetch_add

// fast math: hardware exp/rcp based
__device__ __forceinline__ float rcpf(float x) { return __builtin_amdgcn_rcpf(x); }
__device__ __forceinline__ float sigm(float x) { return rcpf(1.0f + __expf(-x)); }
__device__ __forceinline__ float tanhfast(float x) { return 1.0f - 2.0f * rcpf(1.0f + __expf(2.0f * x)); }

// SC0|SC1 = 17: bypass L1+L2, read/write at the coherent LLC point.
__device__ __forceinline__ void gload16(const void* g, void* l) {
    __builtin_amdgcn_global_load_lds(
        (const __attribute__((address_space(1))) void*)g,
        (__attribute__((address_space(3))) void*)l, 16, 0, 17);
}

__device__ __forceinline__ void store_u16_llc(void* p, unsigned short v) {
    asm volatile("global_store_short %0, %1, off sc0 sc1" :: "v"(p), "v"(v) : "memory");
}
__device__ __forceinline__ void store_f32_llc(void* p, float v) {
    asm volatile("global_store_dword %0, %1, off sc0 sc1" :: "v"(p), "v"(v) : "memory");
}
__device__ __forceinline__ void store_cnt(unsigned* p, unsigned v) {
    asm volatile("global_store_dword %0, %1, off sc0 sc1" :: "v"(p), "v"(v) : "memory");
}

// lane-parallel counter caches: one 64B LLC load refreshes 16 counters.
__device__ __forceinline__ int pollv16(const unsigned* base) {
    return (int)__hip_atomic_load(base + (threadIdx.x & 15),
                                  __ATOMIC_RELAXED, __HIP_MEMORY_SCOPE_AGENT);
}
// lanes 0-31 -> a[lane&15], lanes 32-63 -> b[lane&15]
__device__ __forceinline__ int pollv2(const unsigned* a, const unsigned* b) {
    const unsigned* p = ((threadIdx.x & 32) ? b : a) + (threadIdx.x & 15);
    return (int)__hip_atomic_load(p, __ATOMIC_RELAXED, __HIP_MEMORY_SCOPE_AGENT);
}
__device__ __forceinline__ void wait_min(const unsigned* base, int lanemask,
                                         int tgt, int& seen) {
    while (seen < tgt) {
        unsigned u = __hip_atomic_load(base + (threadIdx.x & lanemask),
                                       __ATOMIC_RELAXED, __HIP_MEMORY_SCOPE_AGENT);
        int x = (int)u;
#pragma unroll
        for (int m = 32; m; m >>= 1) x = min(x, __shfl_xor(x, m, 64));
        seen = x;
        if (seen < tgt) __builtin_amdgcn_s_sleep(2);
    }
}
__device__ __forceinline__ void wait_val(unsigned* p, int tgt, int& seen) {
    while (seen < tgt) {
        seen = (int)__hip_atomic_load(p, __ATOMIC_RELAXED, __HIP_MEMORY_SCOPE_AGENT);
        if (seen < tgt) __builtin_amdgcn_s_sleep(2);
    }
}

__device__ __forceinline__ void cell_update(float zi, float zf, float zg, float zo,
                                            float tt, float tvi, float sv,
                                            float& cp, float& hp)
{
    float ig = sigm(zi), fg = sigm(zf), gg = tanhfast(zg), og = sigm(zo);
    float cc = fg * cp + ig * gg;
    float hc = og * tanhfast(cc);
    float q  = (tt - sv) * tvi;
    float ph = q - floorf(q);                       // == mod(t-s,tau)/tau in [0,1)
    float kg = (ph < 0.025f) ? (ph * 40.0f)
             : (ph < 0.05f ? 2.0f - ph * 40.0f : 0.001f * ph);
    cp = kg * cc + (1.0f - kg) * cp;
    hp = kg * hc + (1.0f - kg) * hp;
}

// Weight prep: bf16 convert + transpose to [n',k] + gate-interleave columns
// n' = unit*4 + gate  <-  orig col = gate*512 + unit
__global__ void prep_kernel(const float* __restrict__ W0, const float* __restrict__ U0,
                            const float* __restrict__ b0, const float* __restrict__ W1,
                            const float* __restrict__ U1, const float* __restrict__ b1,
                            char* __restrict__ ws)
{
    int idx = blockIdx.x * 256 + threadIdx.x;   // 2048*1024 total
    int n = idx >> 10;
    int k = idx & 1023;
    int oc = (n & 3) * UDIM + (n >> 2);
    __hip_bfloat16* U0t = (__hip_bfloat16*)(ws + OFF_U0T);
    __hip_bfloat16* Wc  = (__hip_bfloat16*)(ws + OFF_W1U1T);
    float* W0p = (float*)(ws + OFF_W0P);
    float* b0p = (float*)(ws + OFF_B0P);
    float* b1p = (float*)(ws + OFF_B1P);
    if (k < 512) U0t[(size_t)n * 512 + k] = __float2bfloat16(U0[(size_t)k * NG + oc]);
    float wv = (k < 512) ? W1[(size_t)k * NG + oc] : U1[(size_t)(k - 512) * NG + oc];
    Wc[(size_t)n * 1024 + k] = __float2bfloat16(wv);
    if (k < 3) W0p[k * NG + n] = W0[(size_t)k * NG + oc];
    if (k == 0) { b0p[n] = b0[oc]; b1p[n] = b1[oc]; }
}

// ---------------- layer 0: 64 blocks, tile 128 rows x 128 gate-cols, K=512 ----------------
// Fine-grained RAW: k-chunk l <-> producer l (gate-interleaved layout); each
// staging gload gated on shfl(seenv,l) >= s. Own chunk (j=0, rotated) is free.
// WAR (h0 slot s&3, read by L1@s-3): min32(P1G) >= s-3. Signals own P0G dword.
__device__ void layer0_persist(char* smem, int blk,
    const float* __restrict__ inputs, const float* __restrict__ times,
    const float* __restrict__ tau0, const float* __restrict__ s0v, char* __restrict__ ws)
{
    const int msl = blk >> 4, nsl = blk & 15;
    unsigned* cnt = (unsigned*)(ws + OFF_CNT);
    const unsigned* P0G = cnt + msl * 16;
    const unsigned* P1G = cnt + 64 + msl * 32;
    unsigned* myP0 = cnt + msl * 16 + nsl;
    int seenv = 0, warSeen = 0;
    const int tid = threadIdx.x;
    const int wave = tid >> 6, lane = tid & 63, lr = lane & 15, lq = lane >> 4;
    const int mg = wave >> 2, nw = wave & 3;
    const int colbase = nsl * 128 + nw * 32;

    const __hip_bfloat16* U0t = (const __hip_bfloat16*)(ws + OFF_U0T);
    const float* b0p = (const float*)(ws + OFF_B0P);
    const float* W0p = (const float*)(ws + OFF_W0P);
    __hip_bfloat16* h0b = (__hip_bfloat16*)(ws + OFF_H0B);

    // persistent B fragments, rotated: reg i holds logical k-chunk (nsl+i)&15
    short8 Bf[32];
#pragma unroll
    for (int i = 0; i < 16; ++i) {
        int l = (nsl + i) & 15;
        Bf[i]      = *(const short8*)(U0t + (size_t)(colbase + lr) * 512 + l * 32 + lq * 8);
        Bf[16 + i] = *(const short8*)(U0t + (size_t)(colbase + 16 + lr) * 512 + l * 32 + lq * 8);
    }

    const int cu = tid & 31, crb = tid >> 5;
    const int uu = nsl * 32 + cu;
    const int pcc = nsl * 128 + cu * 4;
    const float4v bias4 = *(const float4v*)(b0p + pcc);
    const float4v w0x = *(const float4v*)(W0p + pcc);
    const float4v w0y = *(const float4v*)(W0p + NG + pcc);
    const float4v w0z = *(const float4v*)(W0p + 2 * NG + pcc);
    const float tvi = 1.0f / tau0[uu], sv = s0v[uu];

    float c0r[8], h0r[8];
#pragma unroll
    for (int i = 0; i < 8; ++i) { c0r[i] = 0.0f; h0r[i] = 0.0f; }

    const int g_row = tid >> 2;
    const int g_q   = (tid & 3) ^ ((g_row >> 1) & 3);

    for (int s = 0; s < TDIM; ++s) {
        if (s >= 4) wait_min(P1G, 31, s - 3, warSeen);   // WAR, rarely binds
        // one refresh attempt at step start (nothing in flight -> no drain cost)
        {
            int x = seenv;
#pragma unroll
            for (int m = 32; m; m >>= 1) x = min(x, __shfl_xor(x, m, 64));
            if (x < s) seenv = pollv16(P0G);
        }

        const __hip_bfloat16* Arow = h0b + ((size_t)((s + 3) & 3)) * HSLOT +
            (size_t)(msl * 128 + g_row) * 512 + g_q * 8;
        __hip_bfloat16* h0w = h0b + ((size_t)(s & 3)) * HSLOT;
        // prologue: tiles 0..5 (rotated; tile 0 = own chunk, no wait)
#pragma unroll
        for (int j = 0; j < 6; ++j) {
            int l = (nsl + j) & 15;
            if (j)
                while (__shfl(seenv, l, 64) < s) {
                    __builtin_amdgcn_s_sleep(1);
                    seenv = pollv16(P0G);
                }
            gload16(Arow + l * 32, smem + j * 8192 + wave * 1024);
        }

        const float4v z4 = {0.0f, 0.0f, 0.0f, 0.0f};
        float4v acc[4][2];
#pragma unroll
        for (int mf = 0; mf < 4; ++mf) { acc[mf][0] = z4; acc[mf][1] = z4; }

#pragma unroll
        for (int I = 0; I < 8; ++I) {
            asm volatile("s_waitcnt vmcnt(%0)" :: "i"((I <= 5) ? 4 : (14 - 2 * I)) : "memory");
            __builtin_amdgcn_s_barrier();
            __builtin_amdgcn_sched_barrier(0);
            if (I < 5) {
                int t0 = 2 * I + 6, t1 = 2 * I + 7;
                int l0 = (nsl + t0) & 15, l1 = (nsl + t1) & 15;
                while (__shfl(seenv, l0, 64) < s) {
                    __builtin_amdgcn_s_sleep(1);
                    seenv = pollv16(P0G);
                }
                while (__shfl(seenv, l1, 64) < s) {
                    __builtin_amdgcn_s_sleep(1);
                    seenv = pollv16(P0G);
                }
                gload16(Arow + l0 * 32, smem + (t0 & 7) * 8192 + wave * 1024);
                gload16(Arow + l1 * 32, smem + (t1 & 7) * 8192 + wave * 1024);
            }
            const short* sA0 = (const short*)(smem + ((2 * I) & 7) * 8192);
            const short* sA1 = (const short*)(smem + ((2 * I + 1) & 7) * 8192);
            short8 aF0[4], aF1[4];
#pragma unroll
            for (int mf = 0; mf < 4; ++mf) {
                int row = mg * 64 + mf * 16 + lr;
                int q = lq ^ ((row >> 1) & 3);
                aF0[mf] = *(const short8*)(sA0 + row * 32 + q * 8);
                aF1[mf] = *(const short8*)(sA1 + row * 32 + q * 8);
            }
#pragma unroll
            for (int mf = 0; mf < 4; ++mf) {
                acc[mf][0] = __builtin_amdgcn_mfma_f32_16x16x32_bf16(aF0[mf], Bf[2 * I],          acc[mf][0], 0, 0, 0);
                acc[mf][1] = __builtin_amdgcn_mfma_f32_16x16x32_bf16(aF0[mf], Bf[16 + 2 * I],     acc[mf][1], 0, 0, 0);
                acc[mf][0] = __builtin_amdgcn_mfma_f32_16x16x32_bf16(aF1[mf], Bf[2 * I + 1],      acc[mf][0], 0, 0, 0);
                acc[mf][1] = __builtin_amdgcn_mfma_f32_16x16x32_bf16(aF1[mf], Bf[16 + 2 * I + 1], acc[mf][1], 0, 0, 0);
            }
        }
        __syncthreads();
        // single-pass epilogue: all 8 waves dump Z[128][132] (67.6KB), one sync
        float* Z = (float*)smem;
#pragma unroll
        for (int mf = 0; mf < 4; ++mf)
#pragma unroll
            for (int nf = 0; nf < 2; ++nf)
#pragma unroll
                for (int i = 0; i < 4; ++i)
                    Z[(mg * 64 + mf * 16 + lq * 4 + i) * 132 + nw * 32 + nf * 16 + lr] = acc[mf][nf][i];
        __syncthreads();
#pragma unroll
        for (int cc = 0; cc < 8; ++cc) {
            int rl = crb + 16 * cc;
            int b = msl * 128 + rl;
            float4v z = *(const float4v*)(Z + rl * 132 + cu * 4);
            const float* xp = inputs + ((size_t)b * TDIM + s) * 3;
            float x0 = xp[0], x1 = xp[1], x2 = xp[2];
            float zi = z[0] + bias4[0] + x0 * w0x[0] + x1 * w0y[0] + x2 * w0z[0];
            float zf = z[1] + bias4[1] + x0 * w0x[1] + x1 * w0y[1] + x2 * w0z[1];
            float zg = z[2] + bias4[2] + x0 * w0x[2] + x1 * w0y[2] + x2 * w0z[2];
            float zo = z[3] + bias4[3] + x0 * w0x[3] + x1 * w0y[3] + x2 * w0z[3];
            float tt = times[(size_t)b * TDIM + s];
            cell_update(zi, zf, zg, zo, tt, tvi, sv, c0r[cc], h0r[cc]);
            __hip_bfloat16 hb = __float2bfloat16(h0r[cc]);
            store_u16_llc(h0w + (size_t)b * 512 + uu, *(unsigned short*)&hb);
        }
        __syncthreads();   // drains all waves' stores (vmcnt(0) before barrier)
        if (tid == 0) store_cnt(myP0, (unsigned)(s + 1));   // single-writer signal
    }
}

// ---------------- layer 1: 128 blocks, tile 64 rows x 128 gate-cols, K=1024 split ----------------
// Fine-grained RAW: A0 tile l -> L0 producers 2l,2l+1 (target s); A1 tile l ->
// h1 peers 2l,2l+1 of own row-half (target s-1). Lane-split counter cache.
// WAR (h1 slot, staged by FC@s-3): PF >= 4(s-4). Signals own P1G dword (=s).
__device__ void layer1_persist(char* smem, int blk,
    const float* __restrict__ times,
    const float* __restrict__ tau1, const float* __restrict__ s1v, char* __restrict__ ws)
{
    const int m8 = blk >> 4, nsl = blk & 15;
    const int grp = m8 >> 1, half = m8 & 1;
    unsigned* cnt = (unsigned*)(ws + OFF_CNT);
    const unsigned* P0G = cnt + grp * 16;
    const unsigned* P1R = cnt + 64 + grp * 32 + half * 16;
    unsigned* myP1 = cnt + 64 + grp * 32 + half * 16 + nsl;
    unsigned* PF = cnt + 192 + grp * 16;
    int sv2 = 0, pfSeen = 0;
    const int tid = threadIdx.x;
    const int wave = tid >> 6, lane = tid & 63, lr = lane & 15, lq = lane >> 4;
    const int kg = wave >> 2, nw = wave & 3;
    const int colbase = nsl * 128 + nw * 32;
    const int r1 = nsl & 7;

    const __hip_bfloat16* Wc = (const __hip_bfloat16*)(ws + OFF_W1U1T);
    const float* b1p = (const float*)(ws + OFF_B1P);
    __hip_bfloat16* h0b = (__hip_bfloat16*)(ws + OFF_H0B);
    __hip_bfloat16* h1b = (__hip_bfloat16*)(ws + OFF_H1B);
    float* h1f = (float*)(ws + OFF_H1F);

    // rotated: reg pair (i*2+kk) holds logical 64-wide chunk (i+r1)&7
    short8 Bf[32];
#pragma unroll
    for (int i = 0; i < 8; ++i) {
        int l = (i + r1) & 7;
#pragma unroll
        for (int kk = 0; kk < 2; ++kk) {
            Bf[i * 2 + kk]      = *(const short8*)(Wc + (size_t)(colbase + lr) * 1024 + kg * 512 + (l * 2 + kk) * 32 + lq * 8);
            Bf[16 + i * 2 + kk] = *(const short8*)(Wc + (size_t)(colbase + 16 + lr) * 1024 + kg * 512 + (l * 2 + kk) * 32 + lq * 8);
        }
    }

    const int cu = tid & 31, crb = tid >> 5;
    const int uu = nsl * 32 + cu;
    const int pcc = nsl * 128 + cu * 4;
    const float4v bias4 = *(const float4v*)(b1p + pcc);
    const float tvi = 1.0f / tau1[uu], svv = s1v[uu];

    float c1r[4], h1r[4];
#pragma unroll
    for (int i = 0; i < 4; ++i) { c1r[i] = 0.0f; h1r[i] = 0.0f; }

    const int g_row = tid >> 3;
    const int g_q   = (tid & 7) ^ (g_row & 7);

    for (int s = 1; s <= TDIM; ++s) {
        const int t = s - 1;
        if (s >= 5) wait_val(PF, 4 * (s - 4), pfSeen);   // WAR, value-cached
        // refresh attempt: per-half min of cached counters vs targets
        {
            int x = sv2;
#pragma unroll
            for (int m = 16; m; m >>= 1) x = min(x, __shfl_xor(x, m, 64));
            bool need = (lane < 32) ? (x < s) : (x < s - 1);
            if (__any(need)) sv2 = pollv2(P0G, P1R);
        }

        const __hip_bfloat16* A0 = h0b + ((size_t)((s + 3) & 3)) * HSLOT +
            (size_t)(m8 * 64 + g_row) * 512 + g_q * 8;
        const __hip_bfloat16* A1 = h1b + ((size_t)((s + 2) & 3)) * HSLOT +
            (size_t)(m8 * 64 + g_row) * 512 + g_q * 8;
        __hip_bfloat16* h1w = h1b + ((size_t)((s + 3) & 3)) * HSLOT;
        float* h1fw = h1f + ((size_t)((s + 3) & 3)) * FSLOT;
#pragma unroll
        for (int J = 0; J < 3; ++J) {
            int l = (J + r1) & 7;
            while (min(__shfl(sv2, 2 * l, 64), __shfl(sv2, 2 * l + 1, 64)) < s) {
                __builtin_amdgcn_s_sleep(1); sv2 = pollv2(P0G, P1R);
            }
            while (min(__shfl(sv2, 32 + 2 * l, 64), __shfl(sv2, 32 + 2 * l + 1, 64)) < s - 1) {
                __builtin_amdgcn_s_sleep(1); sv2 = pollv2(P0G, P1R);
            }
            gload16(A0 + l * 64, smem + (J & 3) * 8192 + wave * 1024);
            gload16(A1 + l * 64, smem + 32768 + (J & 3) * 8192 + wave * 1024);
        }
        const float4v z4 = {0.0f, 0.0f, 0.0f, 0.0f};
        float4v acc[4][2];
#pragma unroll
        for (int mf = 0; mf < 4; ++mf) { acc[mf][0] = z4; acc[mf][1] = z4; }

#pragma unroll
        for (int J = 0; J < 8; ++J) {
            asm volatile("s_waitcnt vmcnt(%0)" :: "i"((J + 2 < 8) ? 4 : ((7 - J) * 2)) : "memory");
            __builtin_amdgcn_s_barrier();
            __builtin_amdgcn_sched_barrier(0);
            if (J + 3 < 8) {
                int l = (J + 3 + r1) & 7;
                while (min(__shfl(sv2, 2 * l, 64), __shfl(sv2, 2 * l + 1, 64)) < s) {
                    __builtin_amdgcn_s_sleep(1); sv2 = pollv2(P0G, P1R);
                }
                while (min(__shfl(sv2, 32 + 2 * l, 64), __shfl(sv2, 32 + 2 * l + 1, 64)) < s - 1) {
                    __builtin_amdgcn_s_sleep(1); sv2 = pollv2(P0G, P1R);
                }
                gload16(A0 + l * 64, smem + ((J + 3) & 3) * 8192 + wave * 1024);
                gload16(A1 + l * 64, smem + 32768 + ((J + 3) & 3) * 8192 + wave * 1024);
            }
            const short* sA = (const short*)(smem + kg * 32768 + (J & 3) * 8192);
#pragma unroll
            for (int kk = 0; kk < 2; ++kk) {
                short8 aF[4];
#pragma unroll
                for (int mf = 0; mf < 4; ++mf) {
                    int row = mf * 16 + lr;
                    int q = (kk * 4 + lq) ^ (row & 7);
                    aF[mf] = *(const short8*)(sA + row * 64 + q * 8);
                }
#pragma unroll
                for (int mf = 0; mf < 4; ++mf) {
                    acc[mf][0] = __builtin_amdgcn_mfma_f32_16x16x32_bf16(aF[mf], Bf[J * 2 + kk],      acc[mf][0], 0, 0, 0);
                    acc[mf][1] = __builtin_amdgcn_mfma_f32_16x16x32_bf16(aF[mf], Bf[16 + J * 2 + kk], acc[mf][1], 0, 0, 0);
                }
            }
        }
        __syncthreads();
        float* Z = (float*)smem;   // zone [64][132] f32 (aliases rings)
        if (kg == 1) {
#pragma unroll
            for (int mf = 0; mf < 4; ++mf)
#pragma unroll
                for (int nf = 0; nf < 2; ++nf)
#pragma unroll
                    for (int i = 0; i < 4; ++i)
                        Z[(mf * 16 + lq * 4 + i) * 132 + nw * 32 + nf * 16 + lr] = acc[mf][nf][i];
        }
        __syncthreads();
        if (kg == 0) {
#pragma unroll
            for (int mf = 0; mf < 4; ++mf)
#pragma unroll
                for (int nf = 0; nf < 2; ++nf)
#pragma unroll
                    for (int i = 0; i < 4; ++i) {
                        int idx = (mf * 16 + lq * 4 + i) * 132 + nw * 32 + nf * 16 + lr;
                        Z[idx] += acc[mf][nf][i];
                    }
        }
        __syncthreads();
#pragma unroll
        for (int cc = 0; cc < 4; ++cc) {
            int rl = crb + 16 * cc;
            int b = m8 * 64 + rl;
            float4v z = *(const float4v*)(Z + rl * 132 + cu * 4);
            float zi = z[0] + bias4[0];
            float zf = z[1] + bias4[1];
            float zg = z[2] + bias4[2];
            float zo = z[3] + bias4[3];
            float tt = times[(size_t)b * TDIM + t];
            cell_update(zi, zf, zg, zo, tt, tvi, svv, c1r[cc], h1r[cc]);
            __hip_bfloat16 hb = __float2bfloat16(h1r[cc]);
            store_u16_llc(h1w + (size_t)b * 512 + uu, *(unsigned short*)&hb);
            store_f32_llc(h1fw + (size_t)b * 512 + uu, h1r[cc]);
        }
        __syncthreads();
        if (tid == 0) store_cnt(myP1, (unsigned)s);   // single-writer signal
    }
}

// ---------------- FC + softmax: 16 blocks x 32 rows ----------------
// RAW h1f[s-2]: min16(P1R row m8=blk>>1) >= s-1. Stages slice into LDS (SC1),
// signals PF right after staging (early ring release), computes from LDS.
__device__ void fc_persist(char* smem, int blk, const float* __restrict__ Wfc,
                           const float* __restrict__ bfc,
                           char* __restrict__ ws, float* __restrict__ out)
{
    const int grp = blk >> 2;
    unsigned* cnt = (unsigned*)(ws + OFF_CNT);
    const unsigned* P1R = cnt + 64 + grp * 32 + ((blk >> 1) & 1) * 16;
    unsigned* PF = cnt + 192 + grp * 16;
    int raw1Seen = 0;
    const int tid = threadIdx.x, wave = tid >> 6, lane = tid & 63;
    const float* h1f = (const float*)(ws + OFF_H1F);
    const int rbase = blk * 32;

    for (int s = 2; s <= TDIM + 1; ++s) {
        int t = s - 2;
        wait_min(P1R, 15, s - 1, raw1Seen);
        const char* h = (const char*)(h1f + ((size_t)((s + 2) & 3)) * FSLOT +
                                      (size_t)rbase * 512);
        // stage 32 rows x 512 f32 = 64KB: 8 chunks of 16B per thread
#pragma unroll
        for (int k = 0; k < 8; ++k)
            gload16(h + ((size_t)(tid + k * 512)) * 16, smem + k * 8192 + wave * 1024);
        asm volatile("s_waitcnt vmcnt(0)" ::: "memory");
        __syncthreads();
        if (tid == 0)
            __hip_atomic_fetch_add(PF, 1u, __ATOMIC_RELAXED, __HIP_MEMORY_SCOPE_AGENT);
        const float* hl = (const float*)smem;
        for (int ri = 0; ri < 4; ++ri) {
            int rl = wave * 4 + ri;
            int row = rbase + rl;
            float a[10];
#pragma unroll
            for (int c = 0; c < 10; ++c) a[c] = 0.0f;
#pragma unroll
            for (int itr = 0; itr < 8; ++itr) {
                float hv = hl[(size_t)rl * 512 + itr * 64 + lane];
                const float* wp = &Wfc[(size_t)(itr * 64 + lane) * 10];
#pragma unroll
                for (int c = 0; c < 10; ++c) a[c] += hv * wp[c];
            }
#pragma unroll
            for (int c = 0; c < 10; ++c)
                for (int m = 32; m; m >>= 1) a[c] += __shfl_xor(a[c], m, 64);
            if (lane == 0) {
                float mx = -1e30f;
#pragma unroll
                for (int c = 0; c < 10; ++c) { a[c] += bfc[c]; mx = fmaxf(mx, a[c]); }
                float sum = 0.0f;
#pragma unroll
                for (int c = 0; c < 10; ++c) { a[c] = __expf(a[c] - mx); sum += a[c]; }
                float inv = 1.0f / sum;
                float* op = &out[((size_t)row * TDIM + t) * 10];
#pragma unroll
                for (int c = 0; c < 10; ++c) op[c] = a[c] * inv;
            }
        }
        __syncthreads();
    }
}

// blocks 0-63: layer0   64-191: layer1   192-207: FC
// Sync: single-writer per-producer counters + per-chunk consume-as-produced
// gating (lane-parallel cached counter vectors). LDS 68KB (2 blocks/CU).
__global__ __launch_bounds__(512, 2)
void persist_kernel(const float* __restrict__ inputs, const float* __restrict__ times,
                    const float* __restrict__ tau0, const float* __restrict__ s0v,
                    const float* __restrict__ tau1, const float* __restrict__ s1v,
                    const float* __restrict__ Wfc, const float* __restrict__ bfc,
                    char* __restrict__ ws, float* __restrict__ out)
{
    __shared__ __align__(16) char smem[69632];
    int blk = blockIdx.x;
    if (blk < 64)       layer0_persist(smem, blk, inputs, times, tau0, s0v, ws);
    else if (blk < 192) layer1_persist(smem, blk - 64, times, tau1, s1v, ws);
    else                fc_persist(smem, blk - 192, Wfc, bfc, ws, out);
}

extern "C" void kernel_launch(void* const* d_in, const int* in_sizes, int n_in,
                              void* d_out, int out_size, void* d_ws, size_t ws_size,
                              hipStream_t stream) {
    const float* inputs = (const float*)d_in[0];
    const float* times  = (const float*)d_in[1];
    const float* W0   = (const float*)d_in[2];
    const float* U0   = (const float*)d_in[3];
    const float* b0   = (const float*)d_in[4];
    const float* tau0 = (const float*)d_in[5];
    const float* s0   = (const float*)d_in[6];
    const float* W1   = (const float*)d_in[7];
    const float* U1   = (const float*)d_in[8];
    const float* b1   = (const float*)d_in[9];
    const float* tau1 = (const float*)d_in[10];
    const float* s1   = (const float*)d_in[11];
    const float* Wfc  = (const float*)d_in[12];
    const float* bfc  = (const float*)d_in[13];
    float* out = (float*)d_out;
    char* ws = (char*)d_ws;

    hipMemsetAsync(ws + OFF_STATE, 0, STATE_BYTES, stream);
    prep_kernel<<<(NG * 1024) / 256, 256, 0, stream>>>(W0, U0, b0, W1, U1, b1, ws);

    void* kargs[] = {(void*)&inputs, (void*)&times, (void*)&tau0, (void*)&s0,
                     (void*)&tau1, (void*)&s1, (void*)&Wfc, (void*)&bfc,
                     (void*)&ws, (void*)&out};
    hipLaunchCooperativeKernel((const void*)persist_kernel, dim3(NBLK), dim3(512),
                               kargs, 0, stream);
}

// Round 9
// 12388.205 us; speedup vs baseline: 1.3898x; 1.3898x over previous
//
#include <hip/hip_runtime.h>
#include <hip/hip_bf16.h>
#include <math.h>

#define TDIM 1024
#define UDIM 512
#define NG   2048   // 4*U
#define NBLK 208

typedef __attribute__((ext_vector_type(8))) short short8;
typedef __attribute__((ext_vector_type(4))) float float4v;

// ---------------- workspace layout ----------------
#define OFF_U0T   ((size_t)0)                       // bf16 [2048][512]  gate-interleaved, transposed
#define SZ_U0T    ((size_t)NG*UDIM*2)
#define OFF_W1U1T (OFF_U0T + SZ_U0T)                // bf16 [2048][1024] (W1 rows 0-511, U1 rows 512-1023)
#define SZ_W1U1T  ((size_t)NG*1024*2)
#define OFF_W0P   (OFF_W1U1T + SZ_W1U1T)            // f32 [3][2048] permuted
#define SZ_W0P    ((size_t)3*NG*4)
#define OFF_B0P   (OFF_W0P + SZ_W0P)
#define OFF_B1P   (OFF_B0P + (size_t)NG*4)
#define OFF_STATE (OFF_B1P + (size_t)NG*4)
#define SZ_HB     ((size_t)512*UDIM*2)              // 512 KB per slot
#define SZ_HF     ((size_t)512*UDIM*4)              // 1 MB per slot
#define OFF_H0B   (OFF_STATE)                       // bf16 ring x4
#define OFF_H1B   (OFF_H0B + 4*SZ_HB)               // bf16 ring x4
#define OFF_H1F   (OFF_H1B + 4*SZ_HB)               // f32 ring x4 (FC input)
#define OFF_CNT   (OFF_H1F + 4*SZ_HF)               // progress counters
#define STATE_BYTES (8*SZ_HB + 4*SZ_HF + 4096)

#define HSLOT ((size_t)512*UDIM)                    // elements per bf16 slot
#define FSLOT ((size_t)512*UDIM)                    // floats per f32 slot

// counter layout (dwords from cnt):
//  P0G:  g*16 + nsl                  [0,64)    L0 per-producer, stores s+1 after step s
//  P1G:  64 + g*32 + half*16 + nsl   [64,192)  L1 per-producer, stores s after step s
//  PF :  192 + g*16                  [192,256) FC aggregated fetch_add

// fast math: hardware exp/rcp based
__device__ __forceinline__ float rcpf(float x) { return __builtin_amdgcn_rcpf(x); }
__device__ __forceinline__ float sigm(float x) { return rcpf(1.0f + __expf(-x)); }
__device__ __forceinline__ float tanhfast(float x) { return 1.0f - 2.0f * rcpf(1.0f + __expf(2.0f * x)); }

// SC0|SC1 = 17: bypass L1+L2, read/write at the coherent LLC point.
__device__ __forceinline__ void gload16(const void* g, void* l) {
    __builtin_amdgcn_global_load_lds(
        (const __attribute__((address_space(1))) void*)g,
        (__attribute__((address_space(3))) void*)l, 16, 0, 17);
}

__device__ __forceinline__ void store_u16_llc(void* p, unsigned short v) {
    asm volatile("global_store_short %0, %1, off sc0 sc1" :: "v"(p), "v"(v) : "memory");
}
__device__ __forceinline__ void store_f32_llc(void* p, float v) {
    asm volatile("global_store_dword %0, %1, off sc0 sc1" :: "v"(p), "v"(v) : "memory");
}
__device__ __forceinline__ void store_cnt(unsigned* p, unsigned v) {
    asm volatile("global_store_dword %0, %1, off sc0 sc1" :: "v"(p), "v"(v) : "memory");
}

// lane-parallel min over 16/32 per-producer counters: one vector load + shfl
// reduce. All waves execute (self-gating, no thread0+syncthreads relay).
__device__ __forceinline__ void wait_min(const unsigned* base, int lanemask,
                                         int tgt, int& seen) {
    while (seen < tgt) {
        unsigned u = __hip_atomic_load(base + (threadIdx.x & lanemask),
                                       __ATOMIC_RELAXED, __HIP_MEMORY_SCOPE_AGENT);
        int x = (int)u;
#pragma unroll
        for (int m = 32; m; m >>= 1) x = min(x, __shfl_xor(x, m, 64));
        seen = x;
        if (seen < tgt) __builtin_amdgcn_s_sleep(2);
    }
}
__device__ __forceinline__ void wait_val(unsigned* p, int tgt, int& seen) {
    while (seen < tgt) {
        seen = (int)__hip_atomic_load(p, __ATOMIC_RELAXED, __HIP_MEMORY_SCOPE_AGENT);
        if (seen < tgt) __builtin_amdgcn_s_sleep(2);
    }
}

__device__ __forceinline__ void cell_update(float zi, float zf, float zg, float zo,
                                            float tt, float tvi, float sv,
                                            float& cp, float& hp)
{
    float ig = sigm(zi), fg = sigm(zf), gg = tanhfast(zg), og = sigm(zo);
    float cc = fg * cp + ig * gg;
    float hc = og * tanhfast(cc);
    float q  = (tt - sv) * tvi;
    float ph = q - floorf(q);                       // == mod(t-s,tau)/tau in [0,1)
    float kg = (ph < 0.025f) ? (ph * 40.0f)
             : (ph < 0.05f ? 2.0f - ph * 40.0f : 0.001f * ph);
    cp = kg * cc + (1.0f - kg) * cp;
    hp = kg * hc + (1.0f - kg) * hp;
}

// Weight prep: bf16 convert + transpose to [n',k] + gate-interleave columns
// n' = unit*4 + gate  <-  orig col = gate*512 + unit
__global__ void prep_kernel(const float* __restrict__ W0, const float* __restrict__ U0,
                            const float* __restrict__ b0, const float* __restrict__ W1,
                            const float* __restrict__ U1, const float* __restrict__ b1,
                            char* __restrict__ ws)
{
    int idx = blockIdx.x * 256 + threadIdx.x;   // 2048*1024 total
    int n = idx >> 10;
    int k = idx & 1023;
    int oc = (n & 3) * UDIM + (n >> 2);
    __hip_bfloat16* U0t = (__hip_bfloat16*)(ws + OFF_U0T);
    __hip_bfloat16* Wc  = (__hip_bfloat16*)(ws + OFF_W1U1T);
    float* W0p = (float*)(ws + OFF_W0P);
    float* b0p = (float*)(ws + OFF_B0P);
    float* b1p = (float*)(ws + OFF_B1P);
    if (k < 512) U0t[(size_t)n * 512 + k] = __float2bfloat16(U0[(size_t)k * NG + oc]);
    float wv = (k < 512) ? W1[(size_t)k * NG + oc] : U1[(size_t)(k - 512) * NG + oc];
    Wc[(size_t)n * 1024 + k] = __float2bfloat16(wv);
    if (k < 3) W0p[k * NG + n] = W0[(size_t)k * NG + oc];
    if (k == 0) { b0p[n] = b0[oc]; b1p[n] = b1[oc]; }
}

// ---------------- layer 0: 64 blocks, tile 128 rows x 128 gate-cols, K=512 ----------------
// Own-chunk staging load hoisted ABOVE the RAW wait (own data always ready) so
// its LLC latency hides under the poll. WAR wait (h0 slot s&3, read by L1@s-3)
// moved to just before the epilogue stores (only they conflict). Signals own
// P0G dword. k-tile order rotated by nsl; 2 tiles per barrier round.
__device__ void layer0_persist(char* smem, int blk,
    const float* __restrict__ inputs, const float* __restrict__ times,
    const float* __restrict__ tau0, const float* __restrict__ s0v, char* __restrict__ ws)
{
    const int msl = blk >> 4, nsl = blk & 15;
    unsigned* cnt = (unsigned*)(ws + OFF_CNT);
    const unsigned* P0G = cnt + msl * 16;
    const unsigned* P1G = cnt + 64 + msl * 32;
    unsigned* myP0 = cnt + msl * 16 + nsl;
    int rawSeen = 0, warSeen = 0;
    const int tid = threadIdx.x;
    const int wave = tid >> 6, lane = tid & 63, lr = lane & 15, lq = lane >> 4;
    const int mg = wave >> 2, nw = wave & 3;
    const int colbase = nsl * 128 + nw * 32;

    const __hip_bfloat16* U0t = (const __hip_bfloat16*)(ws + OFF_U0T);
    const float* b0p = (const float*)(ws + OFF_B0P);
    const float* W0p = (const float*)(ws + OFF_W0P);
    __hip_bfloat16* h0b = (__hip_bfloat16*)(ws + OFF_H0B);

    // persistent B fragments, rotated: reg i holds logical k-chunk (nsl+i)&15
    short8 Bf[32];
#pragma unroll
    for (int i = 0; i < 16; ++i) {
        int l = (nsl + i) & 15;
        Bf[i]      = *(const short8*)(U0t + (size_t)(colbase + lr) * 512 + l * 32 + lq * 8);
        Bf[16 + i] = *(const short8*)(U0t + (size_t)(colbase + 16 + lr) * 512 + l * 32 + lq * 8);
    }

    const int cu = tid & 31, crb = tid >> 5;
    const int uu = nsl * 32 + cu;
    const int pcc = nsl * 128 + cu * 4;
    const float4v bias4 = *(const float4v*)(b0p + pcc);
    const float4v w0x = *(const float4v*)(W0p + pcc);
    const float4v w0y = *(const float4v*)(W0p + NG + pcc);
    const float4v w0z = *(const float4v*)(W0p + 2 * NG + pcc);
    const float tvi = 1.0f / tau0[uu], sv = s0v[uu];

    float c0r[8], h0r[8];
#pragma unroll
    for (int i = 0; i < 8; ++i) { c0r[i] = 0.0f; h0r[i] = 0.0f; }

    const int g_row = tid >> 2;
    const int g_q   = (tid & 3) ^ ((g_row >> 1) & 3);

    for (int s = 0; s < TDIM; ++s) {
        const __hip_bfloat16* Arow = h0b + ((size_t)((s + 3) & 3)) * HSLOT +
            (size_t)(msl * 128 + g_row) * 512 + g_q * 8;
        __hip_bfloat16* h0w = h0b + ((size_t)(s & 3)) * HSLOT;

        // own chunk (tile 0 in rotated order) needs no wait: issue it first so
        // its LLC latency overlaps the RAW poll below.
        gload16(Arow + nsl * 32, smem + wave * 1024);
        wait_min(P0G, 15, s, rawSeen);                   // RAW h0[s-1]
        // remaining prologue tiles 1..5
#pragma unroll
        for (int j = 1; j < 6; ++j)
            gload16(Arow + ((nsl + j) & 15) * 32, smem + j * 8192 + wave * 1024);

        const float4v z4 = {0.0f, 0.0f, 0.0f, 0.0f};
        float4v acc[4][2];
#pragma unroll
        for (int mf = 0; mf < 4; ++mf) { acc[mf][0] = z4; acc[mf][1] = z4; }

#pragma unroll
        for (int I = 0; I < 8; ++I) {
            asm volatile("s_waitcnt vmcnt(%0)" :: "i"((I <= 5) ? 4 : (14 - 2 * I)) : "memory");
            __builtin_amdgcn_s_barrier();
            __builtin_amdgcn_sched_barrier(0);
            if (I < 5) {
                int t0 = 2 * I + 6, t1 = 2 * I + 7;
                gload16(Arow + ((nsl + t0) & 15) * 32, smem + (t0 & 7) * 8192 + wave * 1024);
                gload16(Arow + ((nsl + t1) & 15) * 32, smem + (t1 & 7) * 8192 + wave * 1024);
            }
            const short* sA0 = (const short*)(smem + ((2 * I) & 7) * 8192);
            const short* sA1 = (const short*)(smem + ((2 * I + 1) & 7) * 8192);
            short8 aF0[4], aF1[4];
#pragma unroll
            for (int mf = 0; mf < 4; ++mf) {
                int row = mg * 64 + mf * 16 + lr;
                int q = lq ^ ((row >> 1) & 3);
                aF0[mf] = *(const short8*)(sA0 + row * 32 + q * 8);
                aF1[mf] = *(const short8*)(sA1 + row * 32 + q * 8);
            }
#pragma unroll
            for (int mf = 0; mf < 4; ++mf) {
                acc[mf][0] = __builtin_amdgcn_mfma_f32_16x16x32_bf16(aF0[mf], Bf[2 * I],          acc[mf][0], 0, 0, 0);
                acc[mf][1] = __builtin_amdgcn_mfma_f32_16x16x32_bf16(aF0[mf], Bf[16 + 2 * I],     acc[mf][1], 0, 0, 0);
                acc[mf][0] = __builtin_amdgcn_mfma_f32_16x16x32_bf16(aF1[mf], Bf[2 * I + 1],      acc[mf][0], 0, 0, 0);
                acc[mf][1] = __builtin_amdgcn_mfma_f32_16x16x32_bf16(aF1[mf], Bf[16 + 2 * I + 1], acc[mf][1], 0, 0, 0);
            }
        }
        __syncthreads();
        // WAR: slot s&3 (h0[s-4]) must be consumed by L1@s-3 before overwrite.
        if (s >= 4) wait_min(P1G, 31, s - 3, warSeen);   // rarely binds here
        float* Z = (float*)smem;   // zone [64][132] f32, two passes (aliases ring)
#pragma unroll
        for (int pass = 0; pass < 2; ++pass) {
            if (mg == pass) {
#pragma unroll
                for (int mf = 0; mf < 4; ++mf)
#pragma unroll
                    for (int nf = 0; nf < 2; ++nf)
#pragma unroll
                        for (int i = 0; i < 4; ++i)
                            Z[(mf * 16 + lq * 4 + i) * 132 + nw * 32 + nf * 16 + lr] = acc[mf][nf][i];
            }
            __syncthreads();
#pragma unroll
            for (int cc = 0; cc < 4; ++cc) {
                int rl = crb + 16 * cc;
                int b = msl * 128 + pass * 64 + rl;
                float4v z = *(const float4v*)(Z + rl * 132 + cu * 4);
                const float* xp = inputs + ((size_t)b * TDIM + s) * 3;
                float x0 = xp[0], x1 = xp[1], x2 = xp[2];
                float zi = z[0] + bias4[0] + x0 * w0x[0] + x1 * w0y[0] + x2 * w0z[0];
                float zf = z[1] + bias4[1] + x0 * w0x[1] + x1 * w0y[1] + x2 * w0z[1];
                float zg = z[2] + bias4[2] + x0 * w0x[2] + x1 * w0y[2] + x2 * w0z[2];
                float zo = z[3] + bias4[3] + x0 * w0x[3] + x1 * w0y[3] + x2 * w0z[3];
                float tt = times[(size_t)b * TDIM + s];
                cell_update(zi, zf, zg, zo, tt, tvi, sv, c0r[pass * 4 + cc], h0r[pass * 4 + cc]);
                __hip_bfloat16 hb = __float2bfloat16(h0r[pass * 4 + cc]);
                store_u16_llc(h0w + (size_t)b * 512 + uu, *(unsigned short*)&hb);
            }
            __syncthreads();
        }
        if (tid == 0) store_cnt(myP0, (unsigned)(s + 1));   // single-writer signal
    }
}

// ---------------- layer 1: 128 blocks, tile 64 rows x 128 gate-cols, K=1024 split ----------------
// RAW h0[s-1]: min16(P0G[g]) >= s. RAW h1[s-2]: min16(P1R row m8) >= s-1.
// WAR (h1 slot, staged by FC@s-3) moved to just before epilogue stores.
// Signals own P1G dword (=s).
__device__ void layer1_persist(char* smem, int blk,
    const float* __restrict__ times,
    const float* __restrict__ tau1, const float* __restrict__ s1v, char* __restrict__ ws)
{
    const int m8 = blk >> 4, nsl = blk & 15;
    const int grp = m8 >> 1, half = m8 & 1;
    unsigned* cnt = (unsigned*)(ws + OFF_CNT);
    const unsigned* P0G = cnt + grp * 16;
    const unsigned* P1R = cnt + 64 + grp * 32 + half * 16;
    unsigned* myP1 = cnt + 64 + grp * 32 + half * 16 + nsl;
    unsigned* PF = cnt + 192 + grp * 16;
    int raw0Seen = 0, raw1Seen = 0, pfSeen = 0;
    const int tid = threadIdx.x;
    const int wave = tid >> 6, lane = tid & 63, lr = lane & 15, lq = lane >> 4;
    const int kg = wave >> 2, nw = wave & 3;
    const int colbase = nsl * 128 + nw * 32;
    const int r1 = nsl & 7;

    const __hip_bfloat16* Wc = (const __hip_bfloat16*)(ws + OFF_W1U1T);
    const float* b1p = (const float*)(ws + OFF_B1P);
    __hip_bfloat16* h0b = (__hip_bfloat16*)(ws + OFF_H0B);
    __hip_bfloat16* h1b = (__hip_bfloat16*)(ws + OFF_H1B);
    float* h1f = (float*)(ws + OFF_H1F);

    // rotated: reg pair (i*2+kk) holds logical 64-wide chunk (i+r1)&7
    short8 Bf[32];
#pragma unroll
    for (int i = 0; i < 8; ++i) {
        int l = (i + r1) & 7;
#pragma unroll
        for (int kk = 0; kk < 2; ++kk) {
            Bf[i * 2 + kk]      = *(const short8*)(Wc + (size_t)(colbase + lr) * 1024 + kg * 512 + (l * 2 + kk) * 32 + lq * 8);
            Bf[16 + i * 2 + kk] = *(const short8*)(Wc + (size_t)(colbase + 16 + lr) * 1024 + kg * 512 + (l * 2 + kk) * 32 + lq * 8);
        }
    }

    const int cu = tid & 31, crb = tid >> 5;
    const int uu = nsl * 32 + cu;
    const int pcc = nsl * 128 + cu * 4;
    const float4v bias4 = *(const float4v*)(b1p + pcc);
    const float tvi = 1.0f / tau1[uu], svv = s1v[uu];

    float c1r[4], h1r[4];
#pragma unroll
    for (int i = 0; i < 4; ++i) { c1r[i] = 0.0f; h1r[i] = 0.0f; }

    const int g_row = tid >> 3;
    const int g_q   = (tid & 7) ^ (g_row & 7);

    for (int s = 1; s <= TDIM; ++s) {
        const int t = s - 1;
        wait_min(P0G, 15, s, raw0Seen);
        wait_min(P1R, 15, s - 1, raw1Seen);

        const __hip_bfloat16* A0 = h0b + ((size_t)((s + 3) & 3)) * HSLOT +
            (size_t)(m8 * 64 + g_row) * 512 + g_q * 8;
        const __hip_bfloat16* A1 = h1b + ((size_t)((s + 2) & 3)) * HSLOT +
            (size_t)(m8 * 64 + g_row) * 512 + g_q * 8;
        __hip_bfloat16* h1w = h1b + ((size_t)((s + 3) & 3)) * HSLOT;
        float* h1fw = h1f + ((size_t)((s + 3) & 3)) * FSLOT;
#pragma unroll
        for (int J = 0; J < 3; ++J) {
            int l = (J + r1) & 7;
            gload16(A0 + l * 64, smem + (J & 3) * 8192 + wave * 1024);
            gload16(A1 + l * 64, smem + 32768 + (J & 3) * 8192 + wave * 1024);
        }
        const float4v z4 = {0.0f, 0.0f, 0.0f, 0.0f};
        float4v acc[4][2];
#pragma unroll
        for (int mf = 0; mf < 4; ++mf) { acc[mf][0] = z4; acc[mf][1] = z4; }

#pragma unroll
        for (int J = 0; J < 8; ++J) {
            asm volatile("s_waitcnt vmcnt(%0)" :: "i"((J + 2 < 8) ? 4 : ((7 - J) * 2)) : "memory");
            __builtin_amdgcn_s_barrier();
            __builtin_amdgcn_sched_barrier(0);
            if (J + 3 < 8) {
                int l = (J + 3 + r1) & 7;
                gload16(A0 + l * 64, smem + ((J + 3) & 3) * 8192 + wave * 1024);
                gload16(A1 + l * 64, smem + 32768 + ((J + 3) & 3) * 8192 + wave * 1024);
            }
            const short* sA = (const short*)(smem + kg * 32768 + (J & 3) * 8192);
#pragma unroll
            for (int kk = 0; kk < 2; ++kk) {
                short8 aF[4];
#pragma unroll
                for (int mf = 0; mf < 4; ++mf) {
                    int row = mf * 16 + lr;
                    int q = (kk * 4 + lq) ^ (row & 7);
                    aF[mf] = *(const short8*)(sA + row * 64 + q * 8);
                }
#pragma unroll
                for (int mf = 0; mf < 4; ++mf) {
                    acc[mf][0] = __builtin_amdgcn_mfma_f32_16x16x32_bf16(aF[mf], Bf[J * 2 + kk],      acc[mf][0], 0, 0, 0);
                    acc[mf][1] = __builtin_amdgcn_mfma_f32_16x16x32_bf16(aF[mf], Bf[16 + J * 2 + kk], acc[mf][1], 0, 0, 0);
                }
            }
        }
        __syncthreads();
        // WAR: h1 slot (s+3)&3 (h1[s-5]) must be staged by FC@s-3 first.
        if (s >= 5) wait_val(PF, 4 * (s - 4), pfSeen);   // value-cached, rarely binds
        float* Z = (float*)smem;   // zone [64][132] f32 (aliases rings)
        if (kg == 1) {
#pragma unroll
            for (int mf = 0; mf < 4; ++mf)
#pragma unroll
                for (int nf = 0; nf < 2; ++nf)
#pragma unroll
                    for (int i = 0; i < 4; ++i)
                        Z[(mf * 16 + lq * 4 + i) * 132 + nw * 32 + nf * 16 + lr] = acc[mf][nf][i];
        }
        __syncthreads();
        if (kg == 0) {
#pragma unroll
            for (int mf = 0; mf < 4; ++mf)
#pragma unroll
                for (int nf = 0; nf < 2; ++nf)
#pragma unroll
                    for (int i = 0; i < 4; ++i) {
                        int idx = (mf * 16 + lq * 4 + i) * 132 + nw * 32 + nf * 16 + lr;
                        Z[idx] += acc[mf][nf][i];
                    }
        }
        __syncthreads();
#pragma unroll
        for (int cc = 0; cc < 4; ++cc) {
            int rl = crb + 16 * cc;
            int b = m8 * 64 + rl;
            float4v z = *(const float4v*)(Z + rl * 132 + cu * 4);
            float zi = z[0] + bias4[0];
            float zf = z[1] + bias4[1];
            float zg = z[2] + bias4[2];
            float zo = z[3] + bias4[3];
            float tt = times[(size_t)b * TDIM + t];
            cell_update(zi, zf, zg, zo, tt, tvi, svv, c1r[cc], h1r[cc]);
            __hip_bfloat16 hb = __float2bfloat16(h1r[cc]);
            store_u16_llc(h1w + (size_t)b * 512 + uu, *(unsigned short*)&hb);
            store_f32_llc(h1fw + (size_t)b * 512 + uu, h1r[cc]);
        }
        __syncthreads();
        if (tid == 0) store_cnt(myP1, (unsigned)s);   // single-writer signal
    }
}

// ---------------- FC + softmax: 16 blocks x 32 rows ----------------
// RAW h1f[s-2]: min16(P1R row m8=blk>>1) >= s-1. Stages slice into LDS (SC1),
// signals PF right after staging (early ring release), computes from LDS.
__device__ void fc_persist(char* smem, int blk, const float* __restrict__ Wfc,
                           const float* __restrict__ bfc,
                           char* __restrict__ ws, float* __restrict__ out)
{
    const int grp = blk >> 2;
    unsigned* cnt = (unsigned*)(ws + OFF_CNT);
    const unsigned* P1R = cnt + 64 + grp * 32 + ((blk >> 1) & 1) * 16;
    unsigned* PF = cnt + 192 + grp * 16;
    int raw1Seen = 0;
    const int tid = threadIdx.x, wave = tid >> 6, lane = tid & 63;
    const float* h1f = (const float*)(ws + OFF_H1F);
    const int rbase = blk * 32;

    for (int s = 2; s <= TDIM + 1; ++s) {
        int t = s - 2;
        wait_min(P1R, 15, s - 1, raw1Seen);
        const char* h = (const char*)(h1f + ((size_t)((s + 2) & 3)) * FSLOT +
                                      (size_t)rbase * 512);
        // stage 32 rows x 512 f32 = 64KB: 8 chunks of 16B per thread
#pragma unroll
        for (int k = 0; k < 8; ++k)
            gload16(h + ((size_t)(tid + k * 512)) * 16, smem + k * 8192 + wave * 1024);
        asm volatile("s_waitcnt vmcnt(0)" ::: "memory");
        __syncthreads();
        if (tid == 0)
            __hip_atomic_fetch_add(PF, 1u, __ATOMIC_RELAXED, __HIP_MEMORY_SCOPE_AGENT);
        const float* hl = (const float*)smem;
        for (int ri = 0; ri < 4; ++ri) {
            int rl = wave * 4 + ri;
            int row = rbase + rl;
            float a[10];
#pragma unroll
            for (int c = 0; c < 10; ++c) a[c] = 0.0f;
#pragma unroll
            for (int itr = 0; itr < 8; ++itr) {
                float hv = hl[(size_t)rl * 512 + itr * 64 + lane];
                const float* wp = &Wfc[(size_t)(itr * 64 + lane) * 10];
#pragma unroll
                for (int c = 0; c < 10; ++c) a[c] += hv * wp[c];
            }
#pragma unroll
            for (int c = 0; c < 10; ++c)
                for (int m = 32; m; m >>= 1) a[c] += __shfl_xor(a[c], m, 64);
            if (lane == 0) {
                float mx = -1e30f;
#pragma unroll
                for (int c = 0; c < 10; ++c) { a[c] += bfc[c]; mx = fmaxf(mx, a[c]); }
                float sum = 0.0f;
#pragma unroll
                for (int c = 0; c < 10; ++c) { a[c] = __expf(a[c] - mx); sum += a[c]; }
                float inv = 1.0f / sum;
                float* op = &out[((size_t)row * TDIM + t) * 10];
#pragma unroll
                for (int c = 0; c < 10; ++c) op[c] = a[c] * inv;
            }
        }
        __syncthreads();
    }
}

// blocks 0-63: layer0   64-191: layer1   192-207: FC
// Sync: single-writer per-producer counters (sc0sc1 dword stores) + lane-parallel
// min-reduce waits. WAR waits relocated off the staging critical path.
__global__ __launch_bounds__(512, 2)
void persist_kernel(const float* __restrict__ inputs, const float* __restrict__ times,
                    const float* __restrict__ tau0, const float* __restrict__ s0v,
                    const float* __restrict__ tau1, const float* __restrict__ s1v,
                    const float* __restrict__ Wfc, const float* __restrict__ bfc,
                    char* __restrict__ ws, float* __restrict__ out)
{
    __shared__ __align__(16) char smem[65536];
    int blk = blockIdx.x;
    if (blk < 64)       layer0_persist(smem, blk, inputs, times, tau0, s0v, ws);
    else if (blk < 192) layer1_persist(smem, blk - 64, times, tau1, s1v, ws);
    else                fc_persist(smem, blk - 192, Wfc, bfc, ws, out);
}

extern "C" void kernel_launch(void* const* d_in, const int* in_sizes, int n_in,
                              void* d_out, int out_size, void* d_ws, size_t ws_size,
                              hipStream_t stream) {
    const float* inputs = (const float*)d_in[0];
    const float* times  = (const float*)d_in[1];
    const float* W0   = (const float*)d_in[2];
    const float* U0   = (const float*)d_in[3];
    const float* b0   = (const float*)d_in[4];
    const float* tau0 = (const float*)d_in[5];
    const float* s0   = (const float*)d_in[6];
    const float* W1   = (const float*)d_in[7];
    const float* U1   = (const float*)d_in[8];
    const float* b1   = (const float*)d_in[9];
    const float* tau1 = (const float*)d_in[10];
    const float* s1   = (const float*)d_in[11];
    const float* Wfc  = (const float*)d_in[12];
    const float* bfc  = (const float*)d_in[13];
    float* out = (float*)d_out;
    char* ws = (char*)d_ws;

    hipMemsetAsync(ws + OFF_STATE, 0, STATE_BYTES, stream);
    prep_kernel<<<(NG * 1024) / 256, 256, 0, stream>>>(W0, U0, b0, W1, U1, b1, ws);

    void* kargs[] = {(void*)&inputs, (void*)&times, (void*)&tau0, (void*)&s0,
                     (void*)&tau1, (void*)&s1, (void*)&Wfc, (void*)&bfc,
                     (void*)&ws, (void*)&out};
    hipLaunchCooperativeKernel((const void*)persist_kernel, dim3(NBLK), dim3(512),
                               kargs, 0, stream);
}